// Round 13
// baseline (36.841 us; speedup 1.0000x reference)
//
#include <hip/hip_runtime.h>
#include <math.h>

// Problem shape (fixed by harness reference)
#define B_SZ 32
#define NM   2048     // N == M == 2048
#define D_SZ 32

typedef __attribute__((ext_vector_type(8))) _Float16 h8;   // MFMA A/B frag: 8 f16 = 4 VGPRs
typedef __attribute__((ext_vector_type(4))) float f4;      // MFMA C/D frag

// ---------------------------------------------------------------------------
// Pack X (and Y) into MFMA-fragment-ready f16 layout + fused HALF squared
// norms ph = +0.5*||row||^2 (exact fp32). Fragment layout verified absmax 0.0
// in rounds 2-12: tile t = 16 consecutive rows of flattened [B*NM]; lane l
// holds row t*16+(l&15), k = {4g+j} U {16+4g+j}, g = l>>4.
// ---------------------------------------------------------------------------
__global__ __launch_bounds__(256)
void pack_kernel(const float* __restrict__ srcX, const float* __restrict__ srcY,
                 h8* __restrict__ dstX, h8* __restrict__ dstY,
                 float* __restrict__ phX, float* __restrict__ phY)
{
    const int gid = blockIdx.x * 256 + threadIdx.x;   // one thread per (tile,lane)
    const float* src = blockIdx.y ? srcY : srcX;
    h8*          dst = blockIdx.y ? dstY : dstX;
    float*       ph  = blockIdx.y ? phY  : phX;

    const int l   = gid & 63;
    const int t   = gid >> 6;
    const int row = t * 16 + (l & 15);
    const int k0  = (l >> 4) * 4;

    const float* p = src + (size_t)row * D_SZ;
    f4 v0 = *(const f4*)(p + k0);        // k = k0..k0+3
    f4 v1 = *(const f4*)(p + 16 + k0);   // k = 16+k0..16+k0+3

    h8 h;
    h[0] = (_Float16)v0[0]; h[1] = (_Float16)v0[1];
    h[2] = (_Float16)v0[2]; h[3] = (_Float16)v0[3];
    h[4] = (_Float16)v1[0]; h[5] = (_Float16)v1[1];
    h[6] = (_Float16)v1[2]; h[7] = (_Float16)v1[3];
    dst[gid] = h;

    float s = 0.f;
#pragma unroll
    for (int j = 0; j < 4; ++j) {
        s = fmaf(v0[j], v0[j], s);
        s = fmaf(v1[j], v1[j], s);
    }
    s += __shfl_xor(s, 16);
    s += __shfl_xor(s, 32);
    if (l < 16) ph[row] = 0.5f * s;      // +0.5 * ||row||^2
}

// ---------------------------------------------------------------------------
// FUSED one-pass: computes BOTH directions in a single sweep over the (i,j)
// pair space (halves MFMA, B-loads vs the r6 2-pass structure).
// Symmetric proxy: C-seed hx_i = -0.5*||x||^2[row] (CONSTANT reg tuples per
// wave -> zero per-tile C construction); per element s = q - 0.5*||y||^2[col]
// = -0.5*d^2.  X_inf^2 = -2*max_j s (register fmax + end shuffle, as r6);
// Y_inf^2 = -2*max_i s (per tile: in-lane max3 tree over the lane's 16 s
// values + shfl_xor(16,32) + ONE predicated LDS write; combined cross-wave
// after ONE barrier; one idempotent uint atomicMin per col: s<=0 so
// min-on-uint-bits == max-on-float -> deterministic).
// Grid 512 = 8 row-blocks x 32 b x 2 M-halves, z-major XCD swizzle (verified
// r5), 4 waves/block all sweeping the SAME B-stream, depth-4 prefetch
// (verified r6), __launch_bounds__(256,2) (r12-proven no-spill).
// C/D layout (m89-verified): col=lane&15, row=(lane>>4)*4+reg.
// ---------------------------------------------------------------------------
#define PASS1(BF, PH, T)                                                      \
    {                                                                         \
        f4 q0 = __builtin_amdgcn_mfma_f32_16x16x32_f16(a0, (BF), hx0, 0,0,0); \
        f4 q1 = __builtin_amdgcn_mfma_f32_16x16x32_f16(a1, (BF), hx1, 0,0,0); \
        f4 q2 = __builtin_amdgcn_mfma_f32_16x16x32_f16(a2, (BF), hx2, 0,0,0); \
        f4 q3 = __builtin_amdgcn_mfma_f32_16x16x32_f16(a3, (BF), hx3, 0,0,0); \
        _Pragma("unroll")                                                     \
        for (int r = 0; r < 4; ++r) {                                         \
            q0[r] -= (PH); q1[r] -= (PH); q2[r] -= (PH); q3[r] -= (PH);       \
            mx0[r] = fmaxf(mx0[r], q0[r]);                                    \
            mx1[r] = fmaxf(mx1[r], q1[r]);                                    \
            mx2[r] = fmaxf(mx2[r], q2[r]);                                    \
            mx3[r] = fmaxf(mx3[r], q3[r]);                                    \
        }                                                                     \
        float m0 = fmaxf(fmaxf(q0[0], q0[1]), fmaxf(q0[2], q0[3]));          \
        float m1 = fmaxf(fmaxf(q1[0], q1[1]), fmaxf(q1[2], q1[3]));          \
        float m2 = fmaxf(fmaxf(q2[0], q2[1]), fmaxf(q2[2], q2[3]));          \
        float m3 = fmaxf(fmaxf(q3[0], q3[1]), fmaxf(q3[2], q3[3]));          \
        float cm = fmaxf(fmaxf(m0, m1), fmaxf(m2, m3));                       \
        cm = fmaxf(cm, __shfl_xor(cm, 16));                                   \
        cm = fmaxf(cm, __shfl_xor(cm, 32));                                   \
        if (l < 16) cls[(T)][l][w] = cm;                                      \
    }

__global__ __launch_bounds__(256, 2)
void chamfer_fused(const h8* __restrict__ Xpk, const h8* __restrict__ Ypk,
                   const float* __restrict__ phX, const float* __restrict__ phY,
                   float* __restrict__ mp, unsigned int* __restrict__ colkey)
{
    __shared__ float cls[64][16][4];     // [tile][col-lane][wave] = 16 KB

    // z-major XCD swizzle (nwg = 512, %8 == 0 -> bijective): 8 row-blocks of
    // one (b, mh) group land on one XCD (working set ~1 MB << 4 MB L2).
    const int phys = blockIdx.x;
    const int lg   = (phys & 7) * 64 + (phys >> 3);
    const int xb   = lg & 7;             // 8 row-blocks of 256 rows
    const int rest = lg >> 3;
    const int mh   = rest & 1;           // M-half
    const int b    = rest >> 1;          // batch

    const int tid = threadIdx.x;
    const int w   = tid >> 6;
    const int l   = tid & 63;
    const int lc  = l & 15;
    const int g   = l >> 4;

    const int row0 = xb * 256 + w * 64;                   // within batch
    const size_t pt0 = ((size_t)b * NM + row0) >> 4;      // global 16-row tile
    const h8* pa = Xpk + pt0 * 64 + l;
    h8 a0 = pa[0], a1 = pa[64], a2 = pa[128], a3 = pa[192];

    // Constant C-seed tuples: hx_i[r] = -0.5*||x||^2[row0 + 16i + 4g + r]
    const float* hxb = phX + (size_t)b * NM + row0 + g * 4;
    f4 hx0 = *(const f4*)(hxb);
    f4 hx1 = *(const f4*)(hxb + 16);
    f4 hx2 = *(const f4*)(hxb + 32);
    f4 hx3 = *(const f4*)(hxb + 48);
#pragma unroll
    for (int r = 0; r < 4; ++r) {
        hx0[r] = -hx0[r]; hx1[r] = -hx1[r];
        hx2[r] = -hx2[r]; hx3[r] = -hx3[r];
    }

    const int mt0 = mh * 64;                              // 64 tiles per half
    const h8*    qb  = Ypk + ((size_t)b * (NM / 16) + mt0) * 64 + l;
    const float* php = phY + (size_t)b * NM + mt0 * 16 + lc;

    const float NEGINF = -3.0e38f;
    f4 mx0 = {NEGINF, NEGINF, NEGINF, NEGINF};
    f4 mx1 = mx0, mx2 = mx0, mx3 = mx0;

    // 4-deep register prefetch pipeline over 64 tiles
    h8 b0 = qb[0], b1 = qb[64], b2 = qb[128], b3 = qb[192];
    float c0 = php[0], c1 = php[16], c2 = php[32], c3 = php[48];

    int t = 0;
    for (; t < 60; t += 4) {
        qb += 4 * 64; php += 4 * 16;
        h8 n0 = qb[0], n1 = qb[64], n2 = qb[128], n3 = qb[192];
        float d0 = php[0], d1 = php[16], d2 = php[32], d3 = php[48];
        PASS1(b0, c0, t + 0);
        PASS1(b1, c1, t + 1);
        PASS1(b2, c2, t + 2);
        PASS1(b3, c3, t + 3);
        b0 = n0; b1 = n1; b2 = n2; b3 = n3;
        c0 = d0; c1 = d1; c2 = d2; c3 = d3;
    }
    PASS1(b0, c0, 60);       // tail batch
    PASS1(b1, c1, 61);
    PASS1(b2, c2, 62);
    PASS1(b3, c3, 63);

    // ---- row side: reduce max across the 16 column-lanes, store s-max ----
#pragma unroll
    for (int m = 1; m <= 8; m <<= 1) {
#pragma unroll
        for (int r = 0; r < 4; ++r) {
            mx0[r] = fmaxf(mx0[r], __shfl_xor(mx0[r], m));
            mx1[r] = fmaxf(mx1[r], __shfl_xor(mx1[r], m));
            mx2[r] = fmaxf(mx2[r], __shfl_xor(mx2[r], m));
            mx3[r] = fmaxf(mx3[r], __shfl_xor(mx3[r], m));
        }
    }
    if (lc == 0) {   // rows row0 + i*16 + g*4 .. +3
        float* out = mp + ((size_t)mh * B_SZ + b) * NM + row0 + (g << 2);
        *(f4*)(out)      = mx0;
        *(f4*)(out + 16) = mx1;
        *(f4*)(out + 32) = mx2;
        *(f4*)(out + 48) = mx3;
    }

    // ---- col side: cross-wave combine + one atomicMin per column ----
    __syncthreads();
    unsigned int* ck = colkey + (size_t)b * NM + mh * 1024;
#pragma unroll
    for (int k = 0; k < 4; ++k) {
        int c = tid + k * 256;           // 0..1023 within the half
        f4 v = *(const f4*)&cls[c >> 4][c & 15][0];
        float m = fmaxf(fmaxf(v[0], v[1]), fmaxf(v[2], v[3]));
        // s <= 0: min on uint bits == max on float; idempotent & deterministic
        atomicMin(&ck[c], __float_as_uint(m));
    }
}

// ---------------------------------------------------------------------------
// Finalize: d2 = max(0, -2*smax); sqrt; deterministic two-stage tree sum.
// 32768 work items: first 16384 = row-side f4 (max over 2 M-halves of mp),
// last 16384 = col-side uint4 (bits of winning s).
// ---------------------------------------------------------------------------
__global__ __launch_bounds__(256)
void finalize1(const float* __restrict__ mp, const unsigned int* __restrict__ colkey,
               float* __restrict__ partials)
{
    const int i = blockIdx.x * 256 + threadIdx.x;   // 0..32767
    float s = 0.f;
    if (i < 16384) {
        f4 p0 = ((const f4*)mp)[i];
        f4 p1 = ((const f4*)mp)[16384 + i];
#pragma unroll
        for (int r = 0; r < 4; ++r) {
            float sm = fmaxf(p0[r], p1[r]);
            s += sqrtf(fmaxf(-2.f * sm, 0.f));
        }
    } else {
        const uint4* ck = (const uint4*)colkey;
        uint4 k = ck[i - 16384];
        s += sqrtf(fmaxf(-2.f * __uint_as_float(k.x), 0.f));
        s += sqrtf(fmaxf(-2.f * __uint_as_float(k.y), 0.f));
        s += sqrtf(fmaxf(-2.f * __uint_as_float(k.z), 0.f));
        s += sqrtf(fmaxf(-2.f * __uint_as_float(k.w), 0.f));
    }
    __shared__ float wsum[4];
#pragma unroll
    for (int o = 32; o > 0; o >>= 1) s += __shfl_down(s, o, 64);
    if ((threadIdx.x & 63) == 0) wsum[threadIdx.x >> 6] = s;
    __syncthreads();
    if (threadIdx.x == 0)
        partials[blockIdx.x] = wsum[0] + wsum[1] + wsum[2] + wsum[3];
}

__global__ __launch_bounds__(64)
void finalize2(const float* __restrict__ partials, float* __restrict__ out, float scale)
{
    float s = partials[threadIdx.x] + partials[threadIdx.x + 64];
#pragma unroll
    for (int o = 32; o > 0; o >>= 1) s += __shfl_down(s, o, 64);
    if (threadIdx.x == 0) out[0] = s * scale;
}

extern "C" void kernel_launch(void* const* d_in, const int* in_sizes, int n_in,
                              void* d_out, int out_size, void* d_ws, size_t ws_size,
                              hipStream_t stream) {
    const float* X = (const float*)d_in[0];
    const float* Y = (const float*)d_in[1];

    // ws: mp 131072 f + colkey 65536 u32 + partials 128 f + ph 131072 f
    //     + packed 8.39 MB  (~9.7 MB total)
    float*        ws       = (float*)d_ws;
    float*        mp       = ws;                          // 2 x 32 x 2048 floats
    unsigned int* colkey   = (unsigned int*)(mp + 131072);// 32 x 2048 uints
    float*        partials = (float*)(colkey + 65536);    // 128 floats
    float*        ph       = partials + 128;              // 131072 floats (X then Y)
    h8*           Xpk      = (h8*)(ph + 131072);          // 262144 h8 (4.19 MB)
    h8*           Ypk      = Xpk + 262144;                // 262144 h8 (4.19 MB)

    dim3 pgrid(1024, 2);
    pack_kernel<<<pgrid, 256, 0, stream>>>(X, Y, Xpk, Ypk, ph, ph + 65536);

    // colkey init to 0xFFFFFFFF (max uint; any real s-bits replace it)
    hipMemsetAsync(colkey, 0xFF, 65536 * sizeof(unsigned int), stream);

    // 1D grid: 8 row-blocks x 32 batches x 2 M-halves, XCD-swizzled inside
    chamfer_fused<<<8 * B_SZ * 2, 256, 0, stream>>>(Xpk, Ypk, ph, ph + 65536,
                                                    mp, colkey);

    finalize1<<<128, 256, 0, stream>>>(mp, colkey, partials);
    finalize2<<<1, 64, 0, stream>>>(partials, (float*)d_out, 1.0f / 131072.0f);
}

// Round 14
// 36.551 us; speedup vs baseline: 1.0079x; 1.0079x over previous
//
#include <hip/hip_runtime.h>
#include <math.h>

// Problem shape (fixed by harness reference)
#define B_SZ 32
#define NM   2048     // N == M == 2048
#define D_SZ 32

typedef __attribute__((ext_vector_type(8))) _Float16 h8;   // MFMA A/B frag: 8 f16 = 4 VGPRs
typedef __attribute__((ext_vector_type(4))) float f4;      // MFMA C/D frag

// ---------------------------------------------------------------------------
// Pack X (and Y) into MFMA-fragment-ready f16 layout + fused HALF squared
// norms ph = +0.5*||row||^2 (exact fp32). Fragment layout verified absmax 0.0
// in rounds 2-13. Round 14: also initializes colkey (0xFFFFFFFF) and the
// fixed-point accumulator/counter pair — replaces the separate memset
// dispatch and makes the launch graph 3 kernels instead of 5. Re-inits every
// call (stream-ordered before chamfer/finalize) -> graph-replay safe.
// ---------------------------------------------------------------------------
__global__ __launch_bounds__(256)
void pack_kernel(const float* __restrict__ srcX, const float* __restrict__ srcY,
                 h8* __restrict__ dstX, h8* __restrict__ dstY,
                 float* __restrict__ phX, float* __restrict__ phY,
                 unsigned int* __restrict__ colkey,
                 unsigned long long* __restrict__ acc)
{
    const int gid = blockIdx.x * 256 + threadIdx.x;   // one thread per (tile,lane)
    if (blockIdx.y == 0) {
        if (gid < 65536) colkey[gid] = 0xFFFFFFFFu;   // max uint sentinel
        if (gid < 2)     acc[gid]    = 0ULL;          // [0]=sum, [1]=counter
    }
    const float* src = blockIdx.y ? srcY : srcX;
    h8*          dst = blockIdx.y ? dstY : dstX;
    float*       ph  = blockIdx.y ? phY  : phX;

    const int l   = gid & 63;
    const int t   = gid >> 6;
    const int row = t * 16 + (l & 15);
    const int k0  = (l >> 4) * 4;

    const float* p = src + (size_t)row * D_SZ;
    f4 v0 = *(const f4*)(p + k0);        // k = k0..k0+3
    f4 v1 = *(const f4*)(p + 16 + k0);   // k = 16+k0..16+k0+3

    h8 h;
    h[0] = (_Float16)v0[0]; h[1] = (_Float16)v0[1];
    h[2] = (_Float16)v0[2]; h[3] = (_Float16)v0[3];
    h[4] = (_Float16)v1[0]; h[5] = (_Float16)v1[1];
    h[6] = (_Float16)v1[2]; h[7] = (_Float16)v1[3];
    dst[gid] = h;

    float s = 0.f;
#pragma unroll
    for (int j = 0; j < 4; ++j) {
        s = fmaf(v0[j], v0[j], s);
        s = fmaf(v1[j], v1[j], s);
    }
    s += __shfl_xor(s, 16);
    s += __shfl_xor(s, 32);
    if (l < 16) ph[row] = 0.5f * s;      // +0.5 * ||row||^2
}

// ---------------------------------------------------------------------------
// FUSED one-pass (byte-identical to round 13, verified absmax 0.0): both
// directions in a single sweep. s = dot - 0.5||x||^2 - 0.5||y||^2 = -0.5 d^2.
// Row side: register fmax + end shuffles; col side: per-tile in-lane tree +
// shfl_xor(16,32) + predicated LDS store, cross-wave combine after ONE
// barrier, one idempotent uint atomicMin per column (s<=0: min-on-bits ==
// max-on-float -> deterministic). z-major XCD swizzle (verified r5), 4 waves
// sweep the SAME B-stream, depth-4 prefetch (verified r6), (256,2) no-spill
// (verified r12). C/D layout (m89): col=lane&15, row=(lane>>4)*4+reg.
// ---------------------------------------------------------------------------
#define PASS1(BF, PH, T)                                                      \
    {                                                                         \
        f4 q0 = __builtin_amdgcn_mfma_f32_16x16x32_f16(a0, (BF), hx0, 0,0,0); \
        f4 q1 = __builtin_amdgcn_mfma_f32_16x16x32_f16(a1, (BF), hx1, 0,0,0); \
        f4 q2 = __builtin_amdgcn_mfma_f32_16x16x32_f16(a2, (BF), hx2, 0,0,0); \
        f4 q3 = __builtin_amdgcn_mfma_f32_16x16x32_f16(a3, (BF), hx3, 0,0,0); \
        _Pragma("unroll")                                                     \
        for (int r = 0; r < 4; ++r) {                                         \
            q0[r] -= (PH); q1[r] -= (PH); q2[r] -= (PH); q3[r] -= (PH);       \
            mx0[r] = fmaxf(mx0[r], q0[r]);                                    \
            mx1[r] = fmaxf(mx1[r], q1[r]);                                    \
            mx2[r] = fmaxf(mx2[r], q2[r]);                                    \
            mx3[r] = fmaxf(mx3[r], q3[r]);                                    \
        }                                                                     \
        float m0 = fmaxf(fmaxf(q0[0], q0[1]), fmaxf(q0[2], q0[3]));          \
        float m1 = fmaxf(fmaxf(q1[0], q1[1]), fmaxf(q1[2], q1[3]));          \
        float m2 = fmaxf(fmaxf(q2[0], q2[1]), fmaxf(q2[2], q2[3]));          \
        float m3 = fmaxf(fmaxf(q3[0], q3[1]), fmaxf(q3[2], q3[3]));          \
        float cm = fmaxf(fmaxf(m0, m1), fmaxf(m2, m3));                       \
        cm = fmaxf(cm, __shfl_xor(cm, 16));                                   \
        cm = fmaxf(cm, __shfl_xor(cm, 32));                                   \
        if (l < 16) cls[(T)][l][w] = cm;                                      \
    }

__global__ __launch_bounds__(256, 2)
void chamfer_fused(const h8* __restrict__ Xpk, const h8* __restrict__ Ypk,
                   const float* __restrict__ phX, const float* __restrict__ phY,
                   float* __restrict__ mp, unsigned int* __restrict__ colkey)
{
    __shared__ float cls[64][16][4];     // [tile][col-lane][wave] = 16 KB

    const int phys = blockIdx.x;
    const int lg   = (phys & 7) * 64 + (phys >> 3);
    const int xb   = lg & 7;             // 8 row-blocks of 256 rows
    const int rest = lg >> 3;
    const int mh   = rest & 1;           // M-half
    const int b    = rest >> 1;          // batch

    const int tid = threadIdx.x;
    const int w   = tid >> 6;
    const int l   = tid & 63;
    const int lc  = l & 15;
    const int g   = l >> 4;

    const int row0 = xb * 256 + w * 64;                   // within batch
    const size_t pt0 = ((size_t)b * NM + row0) >> 4;      // global 16-row tile
    const h8* pa = Xpk + pt0 * 64 + l;
    h8 a0 = pa[0], a1 = pa[64], a2 = pa[128], a3 = pa[192];

    // Constant C-seed tuples: hx_i[r] = -0.5*||x||^2[row0 + 16i + 4g + r]
    const float* hxb = phX + (size_t)b * NM + row0 + g * 4;
    f4 hx0 = *(const f4*)(hxb);
    f4 hx1 = *(const f4*)(hxb + 16);
    f4 hx2 = *(const f4*)(hxb + 32);
    f4 hx3 = *(const f4*)(hxb + 48);
#pragma unroll
    for (int r = 0; r < 4; ++r) {
        hx0[r] = -hx0[r]; hx1[r] = -hx1[r];
        hx2[r] = -hx2[r]; hx3[r] = -hx3[r];
    }

    const int mt0 = mh * 64;                              // 64 tiles per half
    const h8*    qb  = Ypk + ((size_t)b * (NM / 16) + mt0) * 64 + l;
    const float* php = phY + (size_t)b * NM + mt0 * 16 + lc;

    const float NEGINF = -3.0e38f;
    f4 mx0 = {NEGINF, NEGINF, NEGINF, NEGINF};
    f4 mx1 = mx0, mx2 = mx0, mx3 = mx0;

    // 4-deep register prefetch pipeline over 64 tiles
    h8 b0 = qb[0], b1 = qb[64], b2 = qb[128], b3 = qb[192];
    float c0 = php[0], c1 = php[16], c2 = php[32], c3 = php[48];

    int t = 0;
    for (; t < 60; t += 4) {
        qb += 4 * 64; php += 4 * 16;
        h8 n0 = qb[0], n1 = qb[64], n2 = qb[128], n3 = qb[192];
        float d0 = php[0], d1 = php[16], d2 = php[32], d3 = php[48];
        PASS1(b0, c0, t + 0);
        PASS1(b1, c1, t + 1);
        PASS1(b2, c2, t + 2);
        PASS1(b3, c3, t + 3);
        b0 = n0; b1 = n1; b2 = n2; b3 = n3;
        c0 = d0; c1 = d1; c2 = d2; c3 = d3;
    }
    PASS1(b0, c0, 60);       // tail batch
    PASS1(b1, c1, 61);
    PASS1(b2, c2, 62);
    PASS1(b3, c3, 63);

    // ---- row side: reduce max across the 16 column-lanes, store s-max ----
#pragma unroll
    for (int m = 1; m <= 8; m <<= 1) {
#pragma unroll
        for (int r = 0; r < 4; ++r) {
            mx0[r] = fmaxf(mx0[r], __shfl_xor(mx0[r], m));
            mx1[r] = fmaxf(mx1[r], __shfl_xor(mx1[r], m));
            mx2[r] = fmaxf(mx2[r], __shfl_xor(mx2[r], m));
            mx3[r] = fmaxf(mx3[r], __shfl_xor(mx3[r], m));
        }
    }
    if (lc == 0) {   // rows row0 + i*16 + g*4 .. +3
        float* out = mp + ((size_t)mh * B_SZ + b) * NM + row0 + (g << 2);
        *(f4*)(out)      = mx0;
        *(f4*)(out + 16) = mx1;
        *(f4*)(out + 32) = mx2;
        *(f4*)(out + 48) = mx3;
    }

    // ---- col side: cross-wave combine + one atomicMin per column ----
    __syncthreads();
    unsigned int* ck = colkey + (size_t)b * NM + mh * 1024;
#pragma unroll
    for (int k = 0; k < 4; ++k) {
        int c = tid + k * 256;           // 0..1023 within the half
        f4 v = *(const f4*)&cls[c >> 4][c & 15][0];
        float m = fmaxf(fmaxf(v[0], v[1]), fmaxf(v[2], v[3]));
        atomicMin(&ck[c], __float_as_uint(m));
    }
}

// ---------------------------------------------------------------------------
// Single merged finalize: d2 = max(0, -2*smax); sqrt; block tree-sum;
// deterministic fixed-point u64 atomicAdd (integer adds commute exactly);
// last-done block (atomic counter + threadfence ordering) writes out[0].
// 32768 work items = 128 blocks x 256 (row side: blocks 0-63; col: 64-127 —
// branch is block-uniform).
// ---------------------------------------------------------------------------
__global__ __launch_bounds__(256)
void finalize_one(const float* __restrict__ mp,
                  const unsigned int* __restrict__ colkey,
                  unsigned long long* __restrict__ acc,
                  float* __restrict__ out)
{
    const int i = blockIdx.x * 256 + threadIdx.x;   // 0..32767
    float s = 0.f;
    if (i < 16384) {
        f4 p0 = ((const f4*)mp)[i];
        f4 p1 = ((const f4*)mp)[16384 + i];
#pragma unroll
        for (int r = 0; r < 4; ++r) {
            float sm = fmaxf(p0[r], p1[r]);
            s += sqrtf(fmaxf(-2.f * sm, 0.f));
        }
    } else {
        const uint4* ck = (const uint4*)colkey;
        uint4 k = ck[i - 16384];
        s += sqrtf(fmaxf(-2.f * __uint_as_float(k.x), 0.f));
        s += sqrtf(fmaxf(-2.f * __uint_as_float(k.y), 0.f));
        s += sqrtf(fmaxf(-2.f * __uint_as_float(k.z), 0.f));
        s += sqrtf(fmaxf(-2.f * __uint_as_float(k.w), 0.f));
    }
    __shared__ float wsum[4];
#pragma unroll
    for (int o = 32; o > 0; o >>= 1) s += __shfl_down(s, o, 64);
    if ((threadIdx.x & 63) == 0) wsum[threadIdx.x >> 6] = s;
    __syncthreads();
    if (threadIdx.x == 0) {
        float bs = wsum[0] + wsum[1] + wsum[2] + wsum[3];
        unsigned long long v =
            (unsigned long long)llrint((double)bs * 1048576.0);
        atomicAdd(&acc[0], v);
        __threadfence();
        unsigned long long c = atomicAdd(&acc[1], 1ULL);
        if (c == 127ULL) {               // last block: total is final
            unsigned long long tot = atomicAdd(&acc[0], 0ULL);
            out[0] = (float)((double)tot * (1.0 / (131072.0 * 1048576.0)));
        }
    }
}

extern "C" void kernel_launch(void* const* d_in, const int* in_sizes, int n_in,
                              void* d_out, int out_size, void* d_ws, size_t ws_size,
                              hipStream_t stream) {
    const float* X = (const float*)d_in[0];
    const float* Y = (const float*)d_in[1];

    // ws: mp 131072 f | colkey 65536 u32 | acc 2 u64 | ph 131072 f | packed
    float*              ws     = (float*)d_ws;
    float*              mp     = ws;                           // 131072 f
    unsigned int*       colkey = (unsigned int*)(mp + 131072); // 65536 u32
    unsigned long long* acc    = (unsigned long long*)(colkey + 65536); // 16 B
    float*              ph     = (float*)(acc + 2);            // 131072 f
    h8*                 Xpk    = (h8*)(ph + 131072);           // 4.19 MB
    h8*                 Ypk    = Xpk + 262144;                 // 4.19 MB

    dim3 pgrid(1024, 2);
    pack_kernel<<<pgrid, 256, 0, stream>>>(X, Y, Xpk, Ypk, ph, ph + 65536,
                                           colkey, acc);

    chamfer_fused<<<8 * B_SZ * 2, 256, 0, stream>>>(Xpk, Ypk, ph, ph + 65536,
                                                    mp, colkey);

    finalize_one<<<128, 256, 0, stream>>>(mp, colkey, acc, (float*)d_out);
}